// Round 13
// baseline (149.257 us; speedup 1.0000x reference)
//
#include <hip/hip_runtime.h>
#include <hip/hip_bf16.h>
#include <stdint.h>

// Problem constants (fixed by setup_inputs)
#define T_SEQ  2048
#define DMODEL 1024
#define NBATCH 2
#define NHEAD  16
#define DHEAD  64
#define MTOT   (NBATCH * T_SEQ)   // 4096 rows for all projection GEMMs

typedef __attribute__((ext_vector_type(8))) short short8_t;   // 8 bf16 (4 VGPRs) MFMA A/B frag
typedef __attribute__((ext_vector_type(4))) float f32x4;      // 16x16 MFMA C/D frag
typedef __attribute__((ext_vector_type(16))) float f32x16;    // 32x32 MFMA C/D frag
typedef __attribute__((ext_vector_type(2))) __bf16 bhalf2_t;
typedef __attribute__((ext_vector_type(4))) uint32_t uint4_t;

typedef const __attribute__((address_space(1))) void* gas_t;
typedef __attribute__((address_space(3))) void* las_t;

// Native f32->bf16 (gfx950 v_cvt_pk_bf16_f32, RNE).
__device__ __forceinline__ ushort f2bf(float f) {
    return __builtin_bit_cast(unsigned short, (__bf16)f);
}
__device__ __forceinline__ uint32_t pk_bf16(float a, float b) {  // one v_cvt_pk_bf16_f32
    bhalf2_t t; t[0] = (__bf16)a; t[1] = (__bf16)b;
    return __builtin_bit_cast(uint32_t, t);
}

// Zero-shuffle P->A-frag: pack 8 consecutive S registers as the frag. The induced
// k->kv permutation pi (swap quads 1<->2 within each 16) is absorbed into the V LDS
// column layout at write time, so no cross-lane exchange is needed at all.
template <int B>
__device__ __forceinline__ short8_t pack8(const f32x16 &s) {
    uint4_t u;
    u[0] = pk_bf16(s[B + 0], s[B + 1]);
    u[1] = pk_bf16(s[B + 2], s[B + 3]);
    u[2] = pk_bf16(s[B + 4], s[B + 5]);
    u[3] = pk_bf16(s[B + 6], s[B + 7]);
    return __builtin_bit_cast(short8_t, u);
}

// ---------------- fp32 -> bf16 convert of q,k,v into one contiguous [3][4096][1024] ----------------
__global__ __launch_bounds__(256) void convert_qkv_kernel(
        const float* __restrict__ q, const float* __restrict__ k,
        const float* __restrict__ v, ushort* __restrict__ outb) {
    const size_t per = (size_t)MTOT * DMODEL / 4;           // float4s per tensor = 1048576
    size_t idx = (size_t)blockIdx.x * 256 + threadIdx.x;
    int t = (int)(idx / per);
    size_t i = idx - (size_t)t * per;
    const float4* src = (const float4*)(t == 0 ? q : (t == 1 ? k : v));
    float4 val = src[i];
    uint2 o;
    o.x = pk_bf16(val.x, val.y);
    o.y = pk_bf16(val.z, val.w);
    ((uint2*)outb)[(size_t)t * per + i] = o;
}

// ---- W fp32 [K][N] -> bf16 transposed [N][K]; Wq gets 1/sqrt(dk)*log2(e) folded in (exp2 domain) --
__global__ __launch_bounds__(256) void convw_kernel(
        const float* __restrict__ Wq, const float* __restrict__ Wk,
        const float* __restrict__ Wv, const float* __restrict__ Wo,
        ushort* __restrict__ wt) {
    __shared__ float tile[32][33];                          // +1 pad: conflict-free transpose
    int z = blockIdx.z;
    const float* W = z == 0 ? Wq : z == 1 ? Wk : z == 2 ? Wv : Wo;
    const float sc = (z == 0) ? 0.18033688011f : 1.0f;      // 0.125 * log2(e)
    ushort* out = wt + (size_t)z * DMODEL * DMODEL;
    int tx = threadIdx.x, ty = threadIdx.y;                 // 32 x 8
    int k0 = blockIdx.x * 32, n0 = blockIdx.y * 32;
    #pragma unroll
    for (int i = 0; i < 4; i++)
        tile[ty + i * 8][tx] = W[(size_t)(k0 + ty + i * 8) * DMODEL + n0 + tx];
    __syncthreads();
    #pragma unroll
    for (int i = 0; i < 4; i++)
        out[(size_t)(n0 + ty + i * 8) * DMODEL + k0 + tx] = f2bf(tile[tx][ty + i * 8] * sc);
}

// ---------------- zero the work-queue counter (run before attn each launch) ----------------
__global__ void zero_ctr_kernel(uint32_t* ctr) {
    if (threadIdx.x == 0 && blockIdx.x == 0) *ctr = 0u;
}

// ---------------- bf16 GEMM, m97 structure: C[M][N] = A[M][K] * Bt[N][K]^T ----------------
template <bool OUT_F32>
__global__ __launch_bounds__(256, 2) void gemm_bt_kernel(
        const ushort* __restrict__ Aall, const ushort* __restrict__ Btall,
        void* __restrict__ Call, int M, int N, int K) {
    const ushort* A  = Aall  + (size_t)blockIdx.z * M * K;
    const ushort* Bt = Btall + (size_t)blockIdx.z * N * K;

    __shared__ ushort As[128 * 32];   // [128 rows][32 k] row-major, 8 KB
    __shared__ ushort Bs[128 * 32];

    const int tid  = threadIdx.x;
    const int lane = tid & 63;
    const int wid  = tid >> 6;
    const int wr = wid >> 1, wc = wid & 1;          // 2x2 wave grid, 64x64 out each
    const int m_base = blockIdx.x * 128;
    const int n_base = blockIdx.y * 128;

    f32x4 acc[4][4] = {};

    const int srow = lane >> 2;                     // staging: 16 rows / chunk
    const int scol = (lane & 3) * 8;                // 4 x 16B per row

    for (int kk = 0; kk < K; kk += 32) {
        __syncthreads();
        #pragma unroll
        for (int i = 0; i < 2; i++) {
            int c = wid * 2 + i;
            const ushort* ga = A  + (size_t)(m_base + c * 16 + srow) * K + kk + scol;
            const ushort* gb = Bt + (size_t)(n_base + c * 16 + srow) * K + kk + scol;
            __builtin_amdgcn_global_load_lds((gas_t)ga, (las_t)(As + c * 512), 16, 0, 0);
            __builtin_amdgcn_global_load_lds((gas_t)gb, (las_t)(Bs + c * 512), 16, 0, 0);
        }
        __syncthreads();
        short8_t a[4], b[4];
        #pragma unroll
        for (int mt = 0; mt < 4; mt++)
            a[mt] = *(const short8_t*)(As + (wr * 64 + mt * 16 + (lane & 15)) * 32 + (lane >> 4) * 8);
        #pragma unroll
        for (int nt = 0; nt < 4; nt++)
            b[nt] = *(const short8_t*)(Bs + (wc * 64 + nt * 16 + (lane & 15)) * 32 + (lane >> 4) * 8);
        #pragma unroll
        for (int mt = 0; mt < 4; mt++)
            #pragma unroll
            for (int nt = 0; nt < 4; nt++)
                acc[mt][nt] = __builtin_amdgcn_mfma_f32_16x16x32_bf16(a[mt], b[nt], acc[mt][nt], 0, 0, 0);
    }

    const int row0 = m_base + wr * 64 + (lane >> 4) * 4;
    const int col0 = n_base + wc * 64 + (lane & 15);
    if constexpr (OUT_F32) {
        float* C = (float*)Call + (size_t)blockIdx.z * M * N;
        #pragma unroll
        for (int mt = 0; mt < 4; mt++)
            #pragma unroll
            for (int nt = 0; nt < 4; nt++)
                #pragma unroll
                for (int r = 0; r < 4; r++)
                    C[(size_t)(row0 + mt * 16 + r) * N + col0 + nt * 16] = acc[mt][nt][r];
    } else {
        ushort* C = (ushort*)Call + (size_t)blockIdx.z * M * N;
        #pragma unroll
        for (int mt = 0; mt < 4; mt++)
            #pragma unroll
            for (int nt = 0; nt < 4; nt++)
                #pragma unroll
                for (int r = 0; r < 4; r++)
                    C[(size_t)(row0 + mt * 16 + r) * N + col0 + nt * 16] = f2bf(acc[mt][nt][r]);
    }
}

// ---------------- causal flash attention: persistent 2-wave blocks + fine-grained queue ----------------
// 1024 persistent 128-thread blocks (4/CU -> 8 waves/CU = 2 INDEPENDENT waves/SIMD).
// Units = (qb 0..63, bh 0..31) = 2048 32-q-row units, pulled heavy-first (qb=63 first) via
// global atomicAdd -> greedy-LPT balance (~66 wave-tiles/CU) under ANY dispatch order.
// Per unit: both waves cover the same 64 q-rows? No -- each wave owns 32 rows: wave w
// handles rows qb*32..qb*32+31 jointly (same unit, same tiles; w splits via... ) -- NO:
// unit = one 64-row q-block? Unit here = one 32-row q-block per WAVE is wrong for shared
// staging; instead unit = 64 q-rows (qb even span): wave w owns rows qb*64+w*32.. (+31).
// nt = qb+1 KV-64 tiles (qb 0..31) -- decoded below as u. Verified R8 core per tile:
// swapped QK^T (mfma_32x32x16), in-register softmax (in-lane tree + shfl_xor(32)),
// zero-shuffle PV with pi baked into V LDS columns, exp2 domain, defer-max, setprio.
// K/V double-buffered (pad-72, 0 conflicts), 1 barrier/tile, reg-prefetch tile t+2.
__global__ __launch_bounds__(128, 2) void attn_kernel(
        const ushort* __restrict__ Qp, const ushort* __restrict__ Kp,
        const ushort* __restrict__ Vp, ushort* __restrict__ Op,
        uint32_t* __restrict__ ctr) {
    __shared__ __attribute__((aligned(16))) ushort Ksh[2][64 * 72];  // [kv][dk], 144B rows
    __shared__ __attribute__((aligned(16))) ushort Vts[2][64 * 72];  // [dv][kv-permuted]
    __shared__ int unit_j;

    const int tid = threadIdx.x, lane = tid & 63, w = tid >> 6;
    const int m31 = lane & 31, hi = lane >> 5;

    // ---- staging decomposition (128 threads; verified R8) ----
    const int kr = tid >> 1, kc64 = (tid & 1) * 32;   // K: row kr, col half kc64
    const int kvp = tid & 31, dvs = tid >> 5;         // V: kv pair, dv 16-chunk (0..3)
    // pi column permutation for V: within each 16-kv block swap quads 1<->2.
    const int lp = kvp & 7, q2 = lp >> 1;
    const int q2p = ((q2 & 1) << 1) | (q2 >> 1);      // 0,1,2,3 -> 0,2,1,3
    const int kvc = (kvp & ~7) | (q2p << 1) | (lp & 1);

    const ushort *Qb, *Kb, *Vb;
    ushort *Ob;
    short8_t kreg[4], vreg[4];
    auto LOADKV = [&](int kv0) {
        #pragma unroll
        for (int j = 0; j < 4; j++)
            kreg[j] = *(const short8_t*)(Kb + (size_t)(kv0 + kr) * DMODEL + kc64 + j * 8);
        const ushort* vsrc = Vb + (size_t)(kv0 + kvp * 2) * DMODEL + dvs * 16;
        vreg[0] = *(const short8_t*)(vsrc);
        vreg[1] = *(const short8_t*)(vsrc + 8);
        vreg[2] = *(const short8_t*)(vsrc + DMODEL);
        vreg[3] = *(const short8_t*)(vsrc + DMODEL + 8);
    };
    auto WRITEKV = [&](int buf) {
        #pragma unroll
        for (int j = 0; j < 4; j++)
            *(short8_t*)(&Ksh[buf][kr * 72 + kc64 + j * 8]) = kreg[j];
        #pragma unroll
        for (int c = 0; c < 2; c++) {
            uint4_t a = __builtin_bit_cast(uint4_t, vreg[c]);      // kv even row
            uint4_t o = __builtin_bit_cast(uint4_t, vreg[2 + c]);  // kv odd row
            #pragma unroll
            for (int j = 0; j < 4; j++) {
                int d0 = dvs * 16 + c * 8 + 2 * j;
                *(uint32_t*)(&Vts[buf][(d0 + 0) * 72 + kvc * 2]) =
                    __builtin_amdgcn_perm(o[j], a[j], 0x05040100u);
                *(uint32_t*)(&Vts[buf][(d0 + 1) * 72 + kvc * 2]) =
                    __builtin_amdgcn_perm(o[j], a[j], 0x07060302u);
            }
        }
    };

    for (;;) {
        __syncthreads();                   // previous unit fully consumed (LDS + unit_j safe)
        if (tid == 0) unit_j = (int)atomicAdd(ctr, 1u);
        __syncthreads();
        const int j = unit_j;
        if (j >= 1024) break;              // units: (u 0..31 heavy-first, bh 0..31)

        const int u = 31 - (j >> 5);       // 64-row q-block index, heavy (u=31) first
        const int bh = j & 31;
        const int b = bh >> 4, h = bh & 15;
        Qb = Qp + (size_t)(b * T_SEQ) * DMODEL + h * DHEAD;
        Kb = Kp + (size_t)(b * T_SEQ) * DMODEL + h * DHEAD;
        Vb = Vp + (size_t)(b * T_SEQ) * DMODEL + h * DHEAD;
        Ob = Op + (size_t)(b * T_SEQ) * DMODEL + h * DHEAD;

        const int nt = u + 1;              // KV-64 tiles (last is diagonal)
        const int q0w = u * 64 + w * 32;   // this wave's 32 q-rows
        const int qg = q0w + m31;
        const int diag = 2 * u + w;        // tile index t where kv0=64t first exceeds... 
        // wave w's rows are [u*64+w*32, u*64+w*32+31]; tile t covers kv [64t, 64t+63].
        // For w=0: rows < u*64+32 -> tile u has kv up to 64u+63 > rows -> mask at t==u? 
        // mask needed for tile t iff 64t+63 > qg_min possible; both waves mask at t==nt-1;
        // wave 0's rows end at u*64+31 < 64u+63 so tile u is partially masked for w=0 too.

        short8_t qf[4];
        #pragma unroll
        for (int dkc = 0; dkc < 4; dkc++)
            qf[dkc] = *(const short8_t*)(Qb + (size_t)(q0w + m31) * DMODEL + dkc * 16 + hi * 8);

        f32x16 acc0 = {}, acc1 = {};       // O[32q][64dv]
        float mrun = -1e30f, lrun = 0.f;

        LOADKV(0);
        WRITEKV(0);                        // safe: barrier above ensures prev unit consumed
        LOADKV(64);                        // tile 1 (rows in-bounds; unused if nt==1)

        for (int t = 0; t < nt; ++t) {
            const int kv0 = t * 64;
            const int cur = t & 1;
            const bool need_mask = (t == nt - 1);

            __syncthreads();               // buf cur writes visible; cur^1 reads complete
            if (t + 1 < nt) {
                WRITEKV(cur ^ 1);          // stage tile t+1, overlaps compute
                if (t + 2 < nt) LOADKV((t + 2) * 64);
            }

            // S^T = K * Q^T: lane holds S^T[kv][q=m31]; reg r -> kv_local =
            // (r&3)+8*(r>>2)+4*hi  [C/D layout m74/m101]
            f32x16 s0 = {}, s1 = {};
            __builtin_amdgcn_s_setprio(1);
            #pragma unroll
            for (int dkc = 0; dkc < 4; dkc++) {
                short8_t kf0 = *(const short8_t*)(&Ksh[cur][(m31) * 72 + dkc * 16 + hi * 8]);
                short8_t kf1 = *(const short8_t*)(&Ksh[cur][(32 + m31) * 72 + dkc * 16 + hi * 8]);
                s0 = __builtin_amdgcn_mfma_f32_32x32x16_bf16(kf0, qf[dkc], s0, 0, 0, 0);
                s1 = __builtin_amdgcn_mfma_f32_32x32x16_bf16(kf1, qf[dkc], s1, 0, 0, 0);
            }
            __builtin_amdgcn_s_setprio(0);

            if (need_mask) {               // causal mask (diagonal tile only)
                const int kvb = kv0 + 4 * hi;
                #pragma unroll
                for (int r = 0; r < 16; r++) {
                    int kvl = (r & 3) + 8 * (r >> 2);
                    if (kvb + kvl      > qg) s0[r] = -1e30f;
                    if (kvb + kvl + 32 > qg) s1[r] = -1e30f;
                }
            }

            float tm[16];
            #pragma unroll
            for (int r = 0; r < 16; r++) tm[r] = fmaxf(s0[r], s1[r]);
            #pragma unroll
            for (int st = 8; st >= 1; st >>= 1)
                #pragma unroll
                for (int i = 0; i < st; i++) tm[i] = fmaxf(tm[i], tm[i + st]);
            float pmax = fmaxf(tm[0], __shfl_xor(tm[0], 32));

            if (!__all(pmax <= mrun + 8.f)) {  // T13 defer-max
                float mnew = fmaxf(mrun, pmax);
                float fac = exp2f(mrun - mnew);
                mrun = mnew;
                lrun *= fac;
                #pragma unroll
                for (int r = 0; r < 16; r++) {
                    float fr = __shfl(fac, (r & 3) + 8 * (r >> 2) + 4 * hi);
                    acc0[r] *= fr; acc1[r] *= fr;
                }
            }
            float ps[16];
            #pragma unroll
            for (int r = 0; r < 16; r++) {
                s0[r] = exp2f(s0[r] - mrun);
                s1[r] = exp2f(s1[r] - mrun);
                ps[r] = s0[r] + s1[r];
            }
            #pragma unroll
            for (int st = 8; st >= 1; st >>= 1)
                #pragma unroll
                for (int i = 0; i < st; i++) ps[i] += ps[i + st];
            lrun += ps[0] + __shfl_xor(ps[0], 32);

            // P -> A-frags (zero-shuffle; V columns pre-permuted), O += P * V
            short8_t pa[4];
            pa[0] = pack8<0>(s0);
            pa[1] = pack8<8>(s0);
            pa[2] = pack8<0>(s1);
            pa[3] = pack8<8>(s1);
            __builtin_amdgcn_s_setprio(1);
            #pragma unroll
            for (int ks = 0; ks < 4; ks++) {
                short8_t vf0 = *(const short8_t*)(&Vts[cur][(m31) * 72 + ks * 16 + hi * 8]);
                short8_t vf1 = *(const short8_t*)(&Vts[cur][(32 + m31) * 72 + ks * 16 + hi * 8]);
                acc0 = __builtin_amdgcn_mfma_f32_32x32x16_bf16(pa[ks], vf0, acc0, 0, 0, 0);
                acc1 = __builtin_amdgcn_mfma_f32_32x32x16_bf16(pa[ks], vf1, acc1, 0, 0, 0);
            }
            __builtin_amdgcn_s_setprio(0);
        }

        // normalize + store: O row q=(r&3)+8(r>>2)+4hi, col dv=m31 / 32+m31
        float linv = __builtin_amdgcn_rcpf(lrun);
        #pragma unroll
        for (int r = 0; r < 16; r++) {
            int ql = (r & 3) + 8 * (r >> 2) + 4 * hi;
            float li = __shfl(linv, ql);
            ushort* orow = Ob + (size_t)(q0w + ql) * DMODEL + m31;
            orow[0]  = f2bf(acc0[r] * li);
            orow[32] = f2bf(acc1[r] * li);
        }
    }
}

// ---------------- launch ----------------
extern "C" void kernel_launch(void* const* d_in, const int* in_sizes, int n_in,
                              void* d_out, int out_size, void* d_ws, size_t ws_size,
                              hipStream_t stream) {
    (void)in_sizes; (void)n_in; (void)out_size; (void)ws_size;
    const float* q  = (const float*)d_in[0];
    const float* k  = (const float*)d_in[1];
    const float* v  = (const float*)d_in[2];
    // d_in[3] = mask (causal tril) -- implemented analytically
    const float* Wq = (const float*)d_in[4];
    const float* Wk = (const float*)d_in[5];
    const float* Wv = (const float*)d_in[6];
    const float* Wo = (const float*)d_in[7];

    ushort* ws = (ushort*)d_ws;
    const size_t MK = (size_t)MTOT * DMODEL;    // 4194304 elems
    const size_t NK = (size_t)DMODEL * DMODEL;  // 1048576 elems
    ushort* qkvb = ws;                    // bf16 q,k,v        [3*MK]   (24 MB)
    ushort* wt   = ws + 3 * MK;           // bf16 W^T x4       [4*NK]   ( 8 MB)
    ushort* qkvp = ws + 3 * MK + 4 * NK;  // bf16 Q,K,V proj   [3*MK]   (24 MB)
    ushort* Op   = ws;                    // attn out reuses qkvb region ( 8 MB)
    uint32_t* ctr = (uint32_t*)(ws + 3 * MK + 4 * NK + 3 * MK);  // work-queue counter

    convert_qkv_kernel<<<dim3(12288), dim3(256), 0, stream>>>(q, k, v, qkvb);
    convw_kernel<<<dim3(32, 32, 4), dim3(32, 8), 0, stream>>>(Wq, Wk, Wv, Wo, wt);
    zero_ctr_kernel<<<dim3(1), dim3(64), 0, stream>>>(ctr);
    gemm_bt_kernel<false><<<dim3(32, 8, 3), dim3(256), 0, stream>>>(qkvb, wt, (void*)qkvp,
                                                                    MTOT, DMODEL, DMODEL);
    attn_kernel<<<dim3(1024), dim3(128), 0, stream>>>(qkvp, qkvp + MK, qkvp + 2 * MK, Op, ctr);
    gemm_bt_kernel<true><<<dim3(32, 8, 1), dim3(256), 0, stream>>>(Op, wt + 3 * NK, d_out,
                                                                   MTOT, DMODEL, DMODEL);
}

// Round 14
// 145.329 us; speedup vs baseline: 1.0270x; 1.0270x over previous
//
#include <hip/hip_runtime.h>
#include <hip/hip_bf16.h>
#include <stdint.h>

// Problem constants (fixed by setup_inputs)
#define T_SEQ  2048
#define DMODEL 1024
#define NBATCH 2
#define NHEAD  16
#define DHEAD  64
#define MTOT   (NBATCH * T_SEQ)   // 4096 rows for all projection GEMMs

typedef __attribute__((ext_vector_type(8))) short short8_t;  // 8 bf16 (4 VGPRs) MFMA A/B frag
typedef __attribute__((ext_vector_type(4))) float f32x4;     // MFMA C/D frag
typedef __attribute__((ext_vector_type(2))) __bf16 bhalf2_t;
typedef __attribute__((ext_vector_type(4))) uint32_t uint4_t;

typedef const __attribute__((address_space(1))) void* gas_t;
typedef __attribute__((address_space(3))) void* las_t;

// Native f32->bf16 (gfx950 v_cvt_pk_bf16_f32, RNE).
__device__ __forceinline__ ushort f2bf(float f) {
    return __builtin_bit_cast(unsigned short, (__bf16)f);
}
__device__ __forceinline__ uint32_t pk_bf16(float a, float b) {  // one v_cvt_pk_bf16_f32
    bhalf2_t t; t[0] = (__bf16)a; t[1] = (__bf16)b;
    return __builtin_bit_cast(uint32_t, t);
}

// Pinned 16B global load: asm volatile cannot be sunk by the scheduler, so the issue
// point in program order is preserved (the compiler kept sinking C++ prefetch loads
// to their use, exposing full load latency every tile -- VGPR counts proved it).
__device__ __forceinline__ short8_t gload16(const ushort* p) {
    short8_t r;
    asm volatile("global_load_dwordx4 %0, %1, off" : "=v"(r) : "v"(p) : "memory");
    return r;
}

// ---------------- fp32 -> bf16 convert of q,k,v into one contiguous [3][4096][1024] ----------------
__global__ __launch_bounds__(256) void convert_qkv_kernel(
        const float* __restrict__ q, const float* __restrict__ k,
        const float* __restrict__ v, ushort* __restrict__ outb) {
    const size_t per = (size_t)MTOT * DMODEL / 4;           // float4s per tensor = 1048576
    size_t idx = (size_t)blockIdx.x * 256 + threadIdx.x;
    int t = (int)(idx / per);
    size_t i = idx - (size_t)t * per;
    const float4* src = (const float4*)(t == 0 ? q : (t == 1 ? k : v));
    float4 val = src[i];
    uint2 o;
    o.x = pk_bf16(val.x, val.y);
    o.y = pk_bf16(val.z, val.w);
    ((uint2*)outb)[(size_t)t * per + i] = o;
}

// ---- W fp32 [K][N] -> bf16 transposed [N][K]; Wq gets 1/sqrt(dk)*log2(e) folded in (exp2 domain) --
__global__ __launch_bounds__(256) void convw_kernel(
        const float* __restrict__ Wq, const float* __restrict__ Wk,
        const float* __restrict__ Wv, const float* __restrict__ Wo,
        ushort* __restrict__ wt) {
    __shared__ float tile[32][33];                          // +1 pad: conflict-free transpose
    int z = blockIdx.z;
    const float* W = z == 0 ? Wq : z == 1 ? Wk : z == 2 ? Wv : Wo;
    const float sc = (z == 0) ? 0.18033688011f : 1.0f;      // 0.125 * log2(e)
    ushort* out = wt + (size_t)z * DMODEL * DMODEL;
    int tx = threadIdx.x, ty = threadIdx.y;                 // 32 x 8
    int k0 = blockIdx.x * 32, n0 = blockIdx.y * 32;
    #pragma unroll
    for (int i = 0; i < 4; i++)
        tile[ty + i * 8][tx] = W[(size_t)(k0 + ty + i * 8) * DMODEL + n0 + tx];
    __syncthreads();
    #pragma unroll
    for (int i = 0; i < 4; i++)
        out[(size_t)(n0 + ty + i * 8) * DMODEL + k0 + tx] = f2bf(tile[tx][ty + i * 8] * sc);
}

// ---------------- bf16 GEMM, m97 structure: C[M][N] = A[M][K] * Bt[N][K]^T ----------------
template <bool OUT_F32>
__global__ __launch_bounds__(256, 2) void gemm_bt_kernel(
        const ushort* __restrict__ Aall, const ushort* __restrict__ Btall,
        void* __restrict__ Call, int M, int N, int K) {
    const ushort* A  = Aall  + (size_t)blockIdx.z * M * K;
    const ushort* Bt = Btall + (size_t)blockIdx.z * N * K;

    __shared__ ushort As[128 * 32];   // [128 rows][32 k] row-major, 8 KB
    __shared__ ushort Bs[128 * 32];

    const int tid  = threadIdx.x;
    const int lane = tid & 63;
    const int wid  = tid >> 6;
    const int wr = wid >> 1, wc = wid & 1;          // 2x2 wave grid, 64x64 out each
    const int m_base = blockIdx.x * 128;
    const int n_base = blockIdx.y * 128;

    f32x4 acc[4][4] = {};

    const int srow = lane >> 2;                     // staging: 16 rows / chunk
    const int scol = (lane & 3) * 8;                // 4 x 16B per row

    for (int kk = 0; kk < K; kk += 32) {
        __syncthreads();
        #pragma unroll
        for (int i = 0; i < 2; i++) {
            int c = wid * 2 + i;
            const ushort* ga = A  + (size_t)(m_base + c * 16 + srow) * K + kk + scol;
            const ushort* gb = Bt + (size_t)(n_base + c * 16 + srow) * K + kk + scol;
            __builtin_amdgcn_global_load_lds((gas_t)ga, (las_t)(As + c * 512), 16, 0, 0);
            __builtin_amdgcn_global_load_lds((gas_t)gb, (las_t)(Bs + c * 512), 16, 0, 0);
        }
        __syncthreads();
        short8_t a[4], b[4];
        #pragma unroll
        for (int mt = 0; mt < 4; mt++)
            a[mt] = *(const short8_t*)(As + (wr * 64 + mt * 16 + (lane & 15)) * 32 + (lane >> 4) * 8);
        #pragma unroll
        for (int nt = 0; nt < 4; nt++)
            b[nt] = *(const short8_t*)(Bs + (wc * 64 + nt * 16 + (lane & 15)) * 32 + (lane >> 4) * 8);
        #pragma unroll
        for (int mt = 0; mt < 4; mt++)
            #pragma unroll
            for (int nt = 0; nt < 4; nt++)
                acc[mt][nt] = __builtin_amdgcn_mfma_f32_16x16x32_bf16(a[mt], b[nt], acc[mt][nt], 0, 0, 0);
    }

    const int row0 = m_base + wr * 64 + (lane >> 4) * 4;
    const int col0 = n_base + wc * 64 + (lane & 15);
    if constexpr (OUT_F32) {
        float* C = (float*)Call + (size_t)blockIdx.z * M * N;
        #pragma unroll
        for (int mt = 0; mt < 4; mt++)
            #pragma unroll
            for (int nt = 0; nt < 4; nt++)
                #pragma unroll
                for (int r = 0; r < 4; r++)
                    C[(size_t)(row0 + mt * 16 + r) * N + col0 + nt * 16] = acc[mt][nt][r];
    } else {
        ushort* C = (ushort*)Call + (size_t)blockIdx.z * M * N;
        #pragma unroll
        for (int mt = 0; mt < 4; mt++)
            #pragma unroll
            for (int nt = 0; nt < 4; nt++)
                #pragma unroll
                for (int r = 0; r < 4; r++)
                    C[(size_t)(row0 + mt * 16 + r) * N + col0 + nt * 16] = f2bf(acc[mt][nt][r]);
    }
}

// ---------------- causal flash attention, balanced pairs + dbuf + PINNED prefetch ----------------
// R6 structure (best measured: 66us): grid (16 pairs, 32 b*h) = 512 blocks, 4 waves.
// Block does q-blocks qa and 31-qa (QBLK=64): exactly 33 KV-tiles. Wave owns 16 q-rows.
// K/V double-buffered (pad-72), 1 barrier/tile. SINGLE CHANGE vs R6: prefetch loads are
// asm-volatile (issue point pinned ~1 full tile ahead of use) + late counted vmcnt(0)
// immediately before WRITEKV (waited loads are a tile old -> wait is ~free). exp2-domain
// softmax, defer-max, setprio, cvt_pk P-pack, v_perm V-transpose.
__global__ __launch_bounds__(256, 2) void attn_kernel(
        const ushort* __restrict__ Qp, const ushort* __restrict__ Kp,
        const ushort* __restrict__ Vp, ushort* __restrict__ Op) {
    __shared__ __attribute__((aligned(16))) ushort Ksh[2][64 * 72];  // [kv][dk], 144B rows
    __shared__ __attribute__((aligned(16))) ushort Vts[2][64 * 72];  // [dv][kv] transposed
    __shared__ __attribute__((aligned(16))) ushort Psh[4][16 * 72];  // per-wave P [16 q][64 kv]

    const int tid = threadIdx.x, lane = tid & 63, w = tid >> 6;
    const int g = lane >> 4;               // 4 lane-groups of 16
    const int m = lane & 15;
    const int bh = blockIdx.y;
    const int b = bh >> 4, h = bh & 15;

    const ushort* Qb = Qp + (size_t)(b * T_SEQ) * DMODEL + h * DHEAD;
    const ushort* Kb = Kp + (size_t)(b * T_SEQ) * DMODEL + h * DHEAD;
    const ushort* Vb = Vp + (size_t)(b * T_SEQ) * DMODEL + h * DHEAD;
    ushort* Ob = Op + (size_t)(b * T_SEQ) * DMODEL + h * DHEAD;

    const int qa = blockIdx.x;             // first (light) q-block
    const int na = qa + 1;                 // tiles for half A; half B: 31-qa -> 32-qa tiles

    // staging decomposition (256 threads)
    const int kr  = tid >> 3, kck = (tid & 7) * 8;   // K: rows kr, kr+32; 16B col chunk
    const int kvp = tid & 31, dvc = tid >> 5;        // V: kv pair, dv 8-chunk

    short8_t kreg0, kreg1, vreg0, vreg1;             // prefetched K/V tile (16 VGPRs, pinned)
    auto LOADKV = [&](int kv0) {
        kreg0 = gload16(Kb + (size_t)(kv0 + kr) * DMODEL + kck);
        kreg1 = gload16(Kb + (size_t)(kv0 + kr + 32) * DMODEL + kck);
        const ushort* vsrc = Vb + (size_t)(kv0 + kvp * 2) * DMODEL + dvc * 8;
        vreg0 = gload16(vsrc);
        vreg1 = gload16(vsrc + DMODEL);
    };
    auto WRITEKV = [&](int buf) {
        *(short8_t*)(&Ksh[buf][kr * 72 + kck]) = kreg0;
        *(short8_t*)(&Ksh[buf][(kr + 32) * 72 + kck]) = kreg1;
        // V transposed, interleave via v_perm_b32
        uint4_t a = __builtin_bit_cast(uint4_t, vreg0);
        uint4_t c = __builtin_bit_cast(uint4_t, vreg1);
        #pragma unroll
        for (int j = 0; j < 4; j++) {
            uint32_t pk0 = __builtin_amdgcn_perm(c[j], a[j], 0x05040100u);  // elem 2j
            uint32_t pk1 = __builtin_amdgcn_perm(c[j], a[j], 0x07060302u);  // elem 2j+1
            *(uint32_t*)(&Vts[buf][(dvc * 8 + 2 * j) * 72 + kvp * 2]) = pk0;
            *(uint32_t*)(&Vts[buf][(dvc * 8 + 2 * j + 1) * 72 + kvp * 2]) = pk1;
        }
    };

    int qi = qa, q0 = qa * 64;
    short8_t qf[2];
    #pragma unroll
    for (int kc = 0; kc < 2; kc++)
        qf[kc] = *(const short8_t*)(Qb + (size_t)(q0 + w * 16 + m) * DMODEL + kc * 32 + g * 8);

    f32x4 acc_o[4] = {};                   // O[q 16][dv 64] per wave
    float mrun = -1e30f, lrun = 0.f;
    ushort* Pw = Psh[w];                   // wave-private P region

    auto WRITE_O = [&]() {
        #pragma unroll
        for (int r = 0; r < 4; r++) {
            float linv = __builtin_amdgcn_rcpf(__shfl(lrun, g * 4 + r));
            int qrow = q0 + w * 16 + g * 4 + r;
            #pragma unroll
            for (int dt = 0; dt < 4; dt++)
                Ob[(size_t)qrow * DMODEL + dt * 16 + m] = f2bf(acc_o[dt][r] * linv);
        }
    };
    auto TILE = [&](int t) { return (t < na) ? t : t - na; };

    // prologue: tile 0 -> regs -> buf0; tile 1 -> regs (issue pinned)
    LOADKV(TILE(0) * 64);
    asm volatile("s_waitcnt vmcnt(0)" ::: "memory");
    __builtin_amdgcn_sched_barrier(0);
    WRITEKV(0);
    LOADKV(TILE(1) * 64);

    for (int tt = 0; tt < 33; ++tt) {
        if (tt == na) {                    // half boundary: finish A, start B
            WRITE_O();
            #pragma unroll
            for (int dt = 0; dt < 4; dt++) acc_o[dt] = f32x4{0.f, 0.f, 0.f, 0.f};
            mrun = -1e30f; lrun = 0.f;
            qi = 31 - qa; q0 = qi * 64;
            #pragma unroll
            for (int kc = 0; kc < 2; kc++)
                qf[kc] = *(const short8_t*)(Qb + (size_t)(q0 + w * 16 + m) * DMODEL + kc * 32 + g * 8);
        }
        const int t = TILE(tt);
        const int kv0 = t * 64;
        const bool need_mask = (t == qi);  // only the diagonal tile is masked
        const int cur = tt & 1;

        __syncthreads();                   // buf cur writes visible; buf cur^1 reads complete
        if (tt + 1 < 33) {
            // late wait: tile tt+1's loads were issued a full tile ago -> ~free
            asm volatile("s_waitcnt vmcnt(0)" ::: "memory");
            __builtin_amdgcn_sched_barrier(0);
            WRITEKV(cur ^ 1);              // stage tile tt+1 (regs -> LDS), overlaps compute
            if (tt + 2 < 33) LOADKV(TILE(tt + 2) * 64);  // pinned issue: hides under tile tt
        }

        // S^T = K * Q^T : lane holds S^T[kv = kvT*16 + g*4 + r][q = m]  (exp2-domain scores)
        f32x4 s[4] = {};
        __builtin_amdgcn_s_setprio(1);
        #pragma unroll
        for (int kvT = 0; kvT < 4; kvT++)
            #pragma unroll
            for (int kc = 0; kc < 2; kc++) {
                short8_t kf = *(const short8_t*)(&Ksh[cur][(kvT * 16 + m) * 72 + kc * 32 + g * 8]);
                s[kvT] = __builtin_amdgcn_mfma_f32_16x16x32_bf16(kf, qf[kc], s[kvT], 0, 0, 0);
            }
        __builtin_amdgcn_s_setprio(0);

        // causal mask (diagonal tile only) + tile max
        const int qg = q0 + w * 16 + m;
        float pmax = -1e30f;
        #pragma unroll
        for (int kvT = 0; kvT < 4; kvT++)
            #pragma unroll
            for (int r = 0; r < 4; r++) {
                float val = s[kvT][r];
                if (need_mask) {
                    int kv_g = kv0 + kvT * 16 + g * 4 + r;
                    if (kv_g > qg) val = -1e30f;
                }
                s[kvT][r] = val;
                pmax = fmaxf(pmax, val);
            }
        pmax = fmaxf(pmax, __shfl_xor(pmax, 16));
        pmax = fmaxf(pmax, __shfl_xor(pmax, 32));
        if (!__all(pmax <= mrun + 8.f)) {  // T13 defer-max: rescale only on real max growth
            float mnew = fmaxf(mrun, pmax);
            float fac = exp2f(mrun - mnew);
            mrun = mnew;
            lrun *= fac;
            #pragma unroll
            for (int r = 0; r < 4; r++) {
                float f = __shfl(fac, g * 4 + r);
                #pragma unroll
                for (int dt = 0; dt < 4; dt++) acc_o[dt][r] *= f;
            }
        }
        float psum = 0.f;
        #pragma unroll
        for (int kvT = 0; kvT < 4; kvT++)
            #pragma unroll
            for (int r = 0; r < 4; r++) {
                float p = exp2f(s[kvT][r] - mrun);   // bounded by 2^8 under defer-max
                s[kvT][r] = p;
                psum += p;
            }
        psum += __shfl_xor(psum, 16);
        psum += __shfl_xor(psum, 32);
        lrun += psum;

        // P (bf16, native cvt_pk) -> wave-private LDS (same-wave write->read, lgkmcnt-ordered)
        #pragma unroll
        for (int kvT = 0; kvT < 4; kvT++) {
            uint2 pk;
            pk.x = pk_bf16(s[kvT][0], s[kvT][1]);
            pk.y = pk_bf16(s[kvT][2], s[kvT][3]);
            *(uint2*)(Pw + m * 72 + kvT * 16 + g * 4) = pk;
        }

        // O += P * V
        short8_t pf[2];
        #pragma unroll
        for (int kc = 0; kc < 2; kc++)
            pf[kc] = *(const short8_t*)(Pw + m * 72 + kc * 32 + g * 8);
        __builtin_amdgcn_s_setprio(1);
        #pragma unroll
        for (int dt = 0; dt < 4; dt++)
            #pragma unroll
            for (int kc = 0; kc < 2; kc++) {
                short8_t vf = *(const short8_t*)(&Vts[cur][(dt * 16 + m) * 72 + kc * 32 + g * 8]);
                acc_o[dt] = __builtin_amdgcn_mfma_f32_16x16x32_bf16(pf[kc], vf, acc_o[dt], 0, 0, 0);
            }
        __builtin_amdgcn_s_setprio(0);
    }
    WRITE_O();
}

// ---------------- launch ----------------
extern "C" void kernel_launch(void* const* d_in, const int* in_sizes, int n_in,
                              void* d_out, int out_size, void* d_ws, size_t ws_size,
                              hipStream_t stream) {
    (void)in_sizes; (void)n_in; (void)out_size; (void)ws_size;
    const float* q  = (const float*)d_in[0];
    const float* k  = (const float*)d_in[1];
    const float* v  = (const float*)d_in[2];
    // d_in[3] = mask (causal tril) -- implemented analytically
    const float* Wq = (const float*)d_in[4];
    const float* Wk = (const float*)d_in[5];
    const float* Wv = (const float*)d_in[6];
    const float* Wo = (const float*)d_in[7];

    ushort* ws = (ushort*)d_ws;
    const size_t MK = (size_t)MTOT * DMODEL;    // 4194304 elems
    const size_t NK = (size_t)DMODEL * DMODEL;  // 1048576 elems
    ushort* qkvb = ws;                    // bf16 q,k,v        [3*MK]   (24 MB)
    ushort* wt   = ws + 3 * MK;           // bf16 W^T x4       [4*NK]   ( 8 MB)
    ushort* qkvp = ws + 3 * MK + 4 * NK;  // bf16 Q,K,V proj   [3*MK]   (24 MB)
    ushort* Op   = ws;                    // attn out reuses qkvb region ( 8 MB)

    convert_qkv_kernel<<<dim3(12288), dim3(256), 0, stream>>>(q, k, v, qkvb);
    convw_kernel<<<dim3(32, 32, 4), dim3(32, 8), 0, stream>>>(Wq, Wk, Wv, Wo, wt);
    gemm_bt_kernel<false><<<dim3(32, 8, 3), dim3(256), 0, stream>>>(qkvb, wt, (void*)qkvp,
                                                                    MTOT, DMODEL, DMODEL);
    attn_kernel<<<dim3(16, 32), dim3(256), 0, stream>>>(qkvp, qkvp + MK, qkvp + 2 * MK, Op);
    gemm_bt_kernel<true><<<dim3(32, 8, 1), dim3(256), 0, stream>>>(Op, wt + 3 * NK, d_out,
                                                                   MTOT, DMODEL, DMODEL);
}